// Round 1
// baseline (910.340 us; speedup 1.0000x reference)
//
#include <hip/hip_runtime.h>
#include <hip/hip_bf16.h>

// Problem constants (from reference)
constexpr int B = 1024, C = 20, N = 26, VDIM = 128, NSPL = 10, NWORDS = 100000;
constexpr int SCORE_BLOCKS = B;          // one block per batch row
constexpr int COPY_BLOCKS  = 3072;       // grid-stride float4 copy of D
constexpr size_t D_ELEMS = (size_t)NSPL * NWORDS * VDIM;   // 128,000,000 floats
constexpr size_t D_F4    = D_ELEMS / 4;                    // 32,000,000 float4
constexpr size_t SCORES_ELEMS = (size_t)B * N;             // 26,624 (16B-aligned *4B)

__global__ __launch_bounds__(256) void dmspline_fused(
    const float* __restrict__ x_vals,       // (B,)
    const int*   __restrict__ knot_ids,     // (B,)
    const int*   __restrict__ context_ids,  // (B, C)
    const int*   __restrict__ tgt_ids,      // (B, N)
    const float* __restrict__ D,            // (NSPL, NWORDS, VDIM)
    const float* __restrict__ W,            // (NWORDS, VDIM)
    const float* __restrict__ O,            // (VDIM, NWORDS)
    float*       __restrict__ out)          // scores (B*N) ++ D (D_ELEMS)
{
    const int bid = blockIdx.x;
    const int tid = threadIdx.x;

    if (bid >= SCORE_BLOCKS) {
        // ---- D -> out copy path (the HBM-bound long pole) ----
        const float4* __restrict__ src = (const float4*)D;
        float4* __restrict__ dst = (float4*)(out + SCORES_ELEMS);
        size_t i = (size_t)(bid - SCORE_BLOCKS) * 256 + tid;
        const size_t stride = (size_t)COPY_BLOCKS * 256;
        for (; i < D_F4; i += stride)
            dst[i] = src[i];
        return;
    }

    // ---- scores path: one block per b ----
    __shared__ float sh_x[VDIM];
    const int b = bid;

    if (tid < VDIM) {
        const float xv   = x_vals[b];
        const int   knot = knot_ids[b];
        const float* __restrict__ Dk = D + (size_t)knot * NWORDS * VDIM + tid;
        const float* __restrict__ Wv = W + tid;
        float acc = 0.f;
        #pragma unroll
        for (int c = 0; c < C; ++c) {
            const int ctx = context_ids[b * C + c];
            acc += Dk[(size_t)ctx * VDIM] * xv + Wv[(size_t)ctx * VDIM];
        }
        sh_x[tid] = acc * (1.0f / C);
    }
    __syncthreads();

    const int wave = tid >> 6;
    const int lane = tid & 63;
    const float x0 = sh_x[lane];
    const float x1 = sh_x[lane + 64];
    const float* __restrict__ O0 = O + (size_t)lane * NWORDS;
    const float* __restrict__ O1 = O + (size_t)(lane + 64) * NWORDS;

    // 4 waves split the N=26 targets round-robin
    for (int n = wave; n < N; n += 4) {
        const int id = tgt_ids[b * N + n];
        float p = x0 * O0[id] + x1 * O1[id];
        #pragma unroll
        for (int m = 32; m >= 1; m >>= 1)
            p += __shfl_xor(p, m, 64);
        if (lane == 0)
            out[(size_t)b * N + n] = p;
    }
}

extern "C" void kernel_launch(void* const* d_in, const int* in_sizes, int n_in,
                              void* d_out, int out_size, void* d_ws, size_t ws_size,
                              hipStream_t stream) {
    const float* x_vals      = (const float*)d_in[0];
    const int*   knot_ids    = (const int*)  d_in[1];
    const int*   context_ids = (const int*)  d_in[2];
    const int*   tgt_ids     = (const int*)  d_in[3];
    const float* D           = (const float*)d_in[4];
    const float* W           = (const float*)d_in[5];
    const float* O           = (const float*)d_in[6];
    float*       out         = (float*)d_out;

    dim3 grid(SCORE_BLOCKS + COPY_BLOCKS);
    dim3 block(256);
    dmspline_fused<<<grid, block, 0, stream>>>(x_vals, knot_ids, context_ids,
                                               tgt_ids, D, W, O, out);
}